// Round 9
// baseline (156.479 us; speedup 1.0000x reference)
//
#include <hip/hip_runtime.h>
#include <math.h>
#include <type_traits>

// ---------------- problem constants ----------------
#define NROWS  23328           // 8 * 54 * 54
#define SPAT   2916            // 54*54
#define HIN    56
#define IMG    3136            // 56*56
#define CIMG   200704          // 64*3136
#define NOUT   2985984         // 23328*128
#define NRB    365             // 64-row blocks (last has 32 valid rows)
#define KH     81              // K32-steps per half

// ---------------- ws layout (bytes) ----------------
#define W2_OFF    0u                         // [648][128][8] bf16 = 1327104
#define ACT8_OFF  1335296u                   // [NPIX][8] bf16 = 25690112
#define SILU_OFF  27025408u                  // [NHW][64] bf16 = 3211264
#define PART_OFF  30236672u                  // [2][NOUT] f32 = 23887872
#define WS_NEED   (PART_OFF + 2u * NOUT * 4u)   // 54.1 MB (proven available)

// prep idx ranges
#define R_SIL_END  200704
#define R_W2_END   864256                    // +663552
#define R_ACT_END  1265664                   // +401408

typedef __bf16 bf16x8 __attribute__((ext_vector_type(8)));
typedef float  floatx4 __attribute__((ext_vector_type(4)));

__device__ __forceinline__ float silu_f(float p) {
    return p / (1.f + __expf(-p));
}

__device__ __forceinline__ bf16x8 bases8(float p) {
    float u  = p * 2.5f + 5.5f;              // uniform grid [-2.2,2.2], h=0.4
    float fk = floorf(u);
    int   kk = (int)fk;
    float t  = u - fk;
    float t2 = t * t, t3 = t2 * t;
    float omt = 1.f - t;
    float w0 = omt * omt * omt * (1.f / 6.f);
    float w1 = (3.f * t3 - 6.f * t2 + 4.f) * (1.f / 6.f);
    float w2 = (-3.f * t3 + 3.f * t2 + 3.f * t + 1.f) * (1.f / 6.f);
    float w3 = t3 * (1.f / 6.f);
    bool inr = (u >= 0.f) && (u < 11.f);
    bf16x8 v;
#pragma unroll
    for (int g = 0; g < 8; ++g) {
        int d = kk - g;
        float val = (d == 3) ? w0 : (d == 2) ? w1
                  : (d == 1) ? w2 : (d == 0) ? w3 : 0.f;
        v[g] = (__bf16)(inr ? val : 0.f);
    }
    return v;
}

// ---------------------------------------------------------------------------
// Prep: silu transpose, W2 planes ([g][cout][8], g = k/8), act8 planes.
// ---------------------------------------------------------------------------
__global__ __launch_bounds__(256) void prep_kernel(
    const float* __restrict__ x, const float* __restrict__ bw,
    const float* __restrict__ sw, const float* __restrict__ sc,
    char* __restrict__ ws)
{
    __bf16* W2    = (__bf16*)(ws + W2_OFF);
    __bf16* act8  = (__bf16*)(ws + ACT8_OFF);
    __bf16* silu_t= (__bf16*)(ws + SILU_OFF);

    int idx = blockIdx.x * 256 + threadIdx.x;
    if (idx < R_SIL_END) {
        int c8 = idx & 7;
        int r  = idx >> 3;                   // b*IMG + hw
        int b  = r / IMG;
        int hw = r - b * IMG;
        const float* xb = x + b * CIMG + (c8 * 8) * IMG + hw;
        bf16x8 v;
#pragma unroll
        for (int j = 0; j < 8; ++j) v[j] = (__bf16)silu_f(xb[j * IMG]);
        *(bf16x8*)(silu_t + (size_t)r * 64 + c8 * 8) = v;
    } else if (idx < R_W2_END) {
        int iw = idx - R_SIL_END;
        int j  = iw & 7;
        int o  = (iw >> 3) & 127;
        int g  = iw >> 10;                   // 0..647
        float val;
        if (g < 576) {
            val = sw[(o * 576 + g) * 8 + j] * sc[o * 576 + g];
        } else {
            int eb = g - 576;
            int rs = eb >> 3;
            int c  = (eb & 7) * 8 + j;
            val = bw[o * 576 + c * 9 + rs];
        }
        W2[iw] = (__bf16)val;
    } else if (idx < R_ACT_END) {
        int i4 = idx - R_W2_END;
        float4 p = ((const float4*)x)[i4];
        __bf16* dst = act8 + (size_t)i4 * 32;
        *(bf16x8*)(dst)      = bases8(p.x);
        *(bf16x8*)(dst + 8)  = bases8(p.y);
        *(bf16x8*)(dst + 16) = bases8(p.z);
        *(bf16x8*)(dst + 24) = bases8(p.w);
    }
}

// ---------------------------------------------------------------------------
// GEMM: 730 blocks = 365 row-blocks x 2 K-halves, 256 threads (4 waves).
// Wave = 64 rows x 32 couts (4x2 acc). NO LDS staging, NO loop barriers:
// A/W fragments are direct 16B register loads, software-pipelined with a
// 3-stage ring (all indices compile-time -> no scratch). Compiler emits
// precise per-register s_waitcnt vmcnt(N) for register loads, which the
// LDS+barrier path structurally cannot do. Offset table in LDS (built once).
// MODE 0: fp32 partials + reduce. MODE 1: atomicAdd fallback.
// ---------------------------------------------------------------------------
template <int MODE>
__global__ __launch_bounds__(256, 3) void kan_gemm(
    char* __restrict__ ws, float* __restrict__ outp)
{
    const __bf16* W2   = (const __bf16*)(ws + W2_OFF);
    float*        part = (float*)(ws + PART_OFF);

    __shared__ int tab[648];                 // byte offsets within region

    const int tid  = threadIdx.x;
    const int lane = tid & 63;
    const int wave = tid >> 6;               // 0..3 = cout group of 32
    const int quad = lane >> 4;
    const int l16  = lane & 15;
    const int half = blockIdx.x & 1;
    const int n0   = (blockIdx.x >> 1) * 64;

    // build offset table (one-time; only barrier in the kernel)
    for (int e = tid; e < 648; e += 256) {
        int off;
        if (e < 576) {                       // act8 plane: pixel offset * 16B
            int c  = e / 9;
            int rs = e - 9 * c;
            int rw = rs / 3;
            off = (c * IMG + rw * HIN + (rs - rw * 3)) * 16;
        } else {                             // silu plane: elem offset * 2B
            int eb = e - 576;
            int rs = eb >> 3;
            int rw = rs / 3;
            off = ((rw * HIN + (rs - rw * 3)) * 64 + (eb & 7) * 8) * 2;
        }
        tab[e] = off;
    }
    __syncthreads();

    // per-lane, per-mt row base byte-offsets into ws
    int abase[4], sbase[4];
#pragma unroll
    for (int mt = 0; mt < 4; ++mt) {
        int nn  = n0 + mt * 16 + l16;
        int ncl = nn < NROWS ? nn : NROWS - 1;
        int bb  = ncl / SPAT;
        int rr  = ncl - bb * SPAT;
        int oh  = rr / 54, ow = rr - (rr / 54) * 54;
        abase[mt] = (int)ACT8_OFF + (bb * CIMG + oh * HIN + ow) * 16;
        sbase[mt] = (int)SILU_OFF + (bb * IMG + oh * HIN + ow) * 128;
    }

    floatx4 acc[4][2] = {};
    const int sAbs0 = half * KH;

    // pipelined span: N compile-time so ring indices constant-fold
    auto runSpan = [&](auto Nc, int sBeg, const int* base) {
        constexpr int N = decltype(Nc)::value;
        bf16x8 A[3][4];
        bf16x8 Wr[3][2];
        auto loadS = [&](int s, int st) {
            int gq   = (sAbs0 + s) * 4 + quad;
            int toff = tab[gq];
#pragma unroll
            for (int mt = 0; mt < 4; ++mt)
                A[st][mt] = *(const bf16x8*)(ws + (unsigned)(base[mt] + toff));
            const __bf16* wp = W2 + ((size_t)gq * 128 + wave * 32 + l16) * 8;
            Wr[st][0] = *(const bf16x8*)(wp);
            Wr[st][1] = *(const bf16x8*)(wp + 128);
        };
        auto mm = [&](int st) {
#pragma unroll
            for (int mt = 0; mt < 4; ++mt)
#pragma unroll
                for (int nt = 0; nt < 2; ++nt)
                    acc[mt][nt] = __builtin_amdgcn_mfma_f32_16x16x32_bf16(
                        Wr[st][nt], A[st][mt], acc[mt][nt], 0, 0, 0);
        };

        loadS(sBeg, 0);
        if constexpr (N > 1) loadS(sBeg + 1, 1);
        constexpr int NB = (N > 2) ? (N - 2) : 0;
        int i = sBeg;
        for (int j = 0; j < NB / 3; ++j) {
            loadS(i + 2, 2); mm(0);
            loadS(i + 3, 0); mm(1);
            loadS(i + 4, 1); mm(2);
            i += 3;
        }
        if constexpr (NB % 3 >= 1) { loadS(i + 2, 2); mm(0); ++i; }
        if constexpr (NB % 3 >= 2) { loadS(i + 2, 0); mm(1); ++i; }
        if constexpr (N >= 2) { mm(NB % 3); mm((NB + 1) % 3); }
        else                  { mm(0); }
    };

    if (half == 0) {
        // g = s*4+quad, s in [0,81): all g < 576 -> act8
        runSpan(std::integral_constant<int, 81>{}, 0, abase);
    } else {
        // g = (81+s)*4+quad: g < 576 iff s < 63
        runSpan(std::integral_constant<int, 63>{}, 0, abase);
        runSpan(std::integral_constant<int, 18>{}, 63, sbase);
    }

    // epilogue: D col(l16) = row n, D row(quad*4+r) = cout -> coalesced
#pragma unroll
    for (int mt = 0; mt < 4; ++mt) {
        int nn = n0 + mt * 16 + l16;
        if (nn < NROWS) {
            int b2   = nn / SPAT;
            int rem2 = nn - b2 * SPAT;
#pragma unroll
            for (int nt = 0; nt < 2; ++nt) {
#pragma unroll
                for (int r = 0; r < 4; ++r) {
                    int o = wave * 32 + nt * 16 + quad * 4 + r;
                    size_t idx = (size_t)(b2 * 128 + o) * SPAT + rem2;
                    float v = acc[mt][nt][r];
                    if (MODE == 0) part[(size_t)half * NOUT + idx] = v;
                    else           atomicAdd(&outp[idx], v);
                }
            }
        }
    }
}

__global__ __launch_bounds__(256) void reduce_kernel(
    const char* __restrict__ ws, float* __restrict__ outp)
{
    const floatx4* p0 = (const floatx4*)(ws + PART_OFF);
    const floatx4* p1 = p0 + NOUT / 4;
    int i = blockIdx.x * 256 + threadIdx.x;   // grid covers NOUT/4 exactly
    floatx4 a = p0[i], b = p1[i];
    ((floatx4*)outp)[i] = (floatx4){a[0] + b[0], a[1] + b[1],
                                    a[2] + b[2], a[3] + b[3]};
}

__global__ __launch_bounds__(256) void zero_kernel(float* __restrict__ outp)
{
    int i = blockIdx.x * 256 + threadIdx.x;
    ((floatx4*)outp)[i] = (floatx4){0.f, 0.f, 0.f, 0.f};
}

extern "C" void kernel_launch(void* const* d_in, const int* in_sizes, int n_in,
                              void* d_out, int out_size, void* d_ws, size_t ws_size,
                              hipStream_t stream) {
    const float* x  = (const float*)d_in[0];
    const float* bw = (const float*)d_in[1];
    const float* sw = (const float*)d_in[2];
    const float* sc = (const float*)d_in[3];
    float* out = (float*)d_out;
    char*  ws  = (char*)d_ws;

    prep_kernel<<<R_ACT_END / 256, 256, 0, stream>>>(x, bw, sw, sc, ws);

    if (ws_size >= WS_NEED) {
        kan_gemm<0><<<NRB * 2, 256, 0, stream>>>(ws, out);
        reduce_kernel<<<NOUT / 4 / 256, 256, 0, stream>>>(ws, out);
    } else {
        zero_kernel<<<NOUT / 4 / 256, 256, 0, stream>>>(out);
        kan_gemm<1><<<NRB * 2, 256, 0, stream>>>(ws, out);
    }
}

// Round 10
// 138.763 us; speedup vs baseline: 1.1277x; 1.1277x over previous
//
#include <hip/hip_runtime.h>
#include <math.h>

// ---------------- problem constants ----------------
#define NROWS  23328           // 8 * 54 * 54
#define SPAT   2916            // 54*54 rows per batch
#define HIN    56
#define IMG    3136            // 56*56
#define CIMG   200704          // 64*3136
#define NOUT   2985984         // 23328*128
#define RBPB   46              // 64-row blocks per batch (last has 36 valid)
#define NCH    27              // chunks per K-half (81 K32-steps / 3)

// ---------------- ws layout (bytes) ----------------
#define W2_OFF    0u                         // [648][128][8] bf16 = 1327104
#define ACT8_OFF  1335296u                   // [NPIX][8] bf16 = 25690112
#define SILU_OFF  27025408u                  // [NHW][64] bf16 = 3211264
#define PART_OFF  30236672u                  // [2][NOUT] f32 = 23887872
#define WS_NEED   (PART_OFF + 2u * NOUT * 4u)   // 54.1 MB (proven available)

// prep idx ranges
#define R_SIL_END  200704
#define R_W2_END   864256                    // +663552
#define R_ACT_END  1265664                   // +401408

typedef __bf16 bf16x8 __attribute__((ext_vector_type(8)));
typedef float  floatx4 __attribute__((ext_vector_type(4)));

#define GL2LDS(SRC, DST) __builtin_amdgcn_global_load_lds( \
    (const __attribute__((address_space(1))) unsigned int*)(SRC), \
    (__attribute__((address_space(3))) unsigned int*)(DST), 16, 0, 0)

__device__ __forceinline__ float silu_f(float p) {
    return p / (1.f + __expf(-p));
}

__device__ __forceinline__ bf16x8 bases8(float p) {
    float u  = p * 2.5f + 5.5f;              // uniform grid [-2.2,2.2], h=0.4
    float fk = floorf(u);
    int   kk = (int)fk;
    float t  = u - fk;
    float t2 = t * t, t3 = t2 * t;
    float omt = 1.f - t;
    float w0 = omt * omt * omt * (1.f / 6.f);
    float w1 = (3.f * t3 - 6.f * t2 + 4.f) * (1.f / 6.f);
    float w2 = (-3.f * t3 + 3.f * t2 + 3.f * t + 1.f) * (1.f / 6.f);
    float w3 = t3 * (1.f / 6.f);
    bool inr = (u >= 0.f) && (u < 11.f);
    bf16x8 v;
#pragma unroll
    for (int g = 0; g < 8; ++g) {
        int d = kk - g;
        float val = (d == 3) ? w0 : (d == 2) ? w1
                  : (d == 1) ? w2 : (d == 0) ? w3 : 0.f;
        v[g] = (__bf16)(inr ? val : 0.f);
    }
    return v;
}

// ---------------------------------------------------------------------------
// Prep: silu transpose, W2 planes ([g][cout][8], g = k/8), act8 planes.
// ---------------------------------------------------------------------------
__global__ __launch_bounds__(256) void prep_kernel(
    const float* __restrict__ x, const float* __restrict__ bw,
    const float* __restrict__ sw, const float* __restrict__ sc,
    char* __restrict__ ws)
{
    __bf16* W2    = (__bf16*)(ws + W2_OFF);
    __bf16* act8  = (__bf16*)(ws + ACT8_OFF);
    __bf16* silu_t= (__bf16*)(ws + SILU_OFF);

    int idx = blockIdx.x * 256 + threadIdx.x;
    if (idx < R_SIL_END) {
        int c8 = idx & 7;
        int r  = idx >> 3;                   // b*IMG + hw
        int b  = r / IMG;
        int hw = r - b * IMG;
        const float* xb = x + b * CIMG + (c8 * 8) * IMG + hw;
        bf16x8 v;
#pragma unroll
        for (int j = 0; j < 8; ++j) v[j] = (__bf16)silu_f(xb[j * IMG]);
        *(bf16x8*)(silu_t + (size_t)r * 64 + c8 * 8) = v;
    } else if (idx < R_W2_END) {
        int iw = idx - R_SIL_END;
        int j  = iw & 7;
        int o  = (iw >> 3) & 127;
        int g  = iw >> 10;                   // 0..647
        float val;
        if (g < 576) {
            val = sw[(o * 576 + g) * 8 + j] * sc[o * 576 + g];
        } else {
            int eb = g - 576;
            int rs = eb >> 3;
            int c  = (eb & 7) * 8 + j;
            val = bw[o * 576 + c * 9 + rs];
        }
        W2[iw] = (__bf16)val;
    } else if (idx < R_ACT_END) {
        int i4 = idx - R_W2_END;
        float4 p = ((const float4*)x)[i4];
        __bf16* dst = act8 + (size_t)i4 * 32;
        *(bf16x8*)(dst)      = bases8(p.x);
        *(bf16x8*)(dst + 8)  = bases8(p.y);
        *(bf16x8*)(dst + 16) = bases8(p.z);
        *(bf16x8*)(dst + 24) = bases8(p.w);
    }
}

// ---------------------------------------------------------------------------
// GEMM: 736 blocks = 8 batches x 46 row-blocks x 2 K-halves, 512 threads
// (8 waves). batch = blockIdx & 7 -> batch-per-XCD: per-XCD act8+silu+W
// working set ~4.9 MB ~ L2-resident (A-loads L2-hit instead of L3).
// Block = 64 rows x 128 couts x half-K; wave = 32 rows x 32 couts (2x2 acc).
// A staged by async global_load_lds, double-buffered, 3 K32-steps per chunk,
// one barrier per chunk. MODE 0: fp32 partials + reduce. MODE 1: atomicAdd.
// ---------------------------------------------------------------------------
template <int MODE>
__global__ __launch_bounds__(512, 4) void kan_gemm(
    char* __restrict__ ws, float* __restrict__ outp)
{
    const __bf16* W2     = (const __bf16*)(ws + W2_OFF);
    const __bf16* act8   = (const __bf16*)(ws + ACT8_OFF);
    const __bf16* silu_t = (const __bf16*)(ws + SILU_OFF);
    float*        part   = (float*)(ws + PART_OFF);

    __shared__ __align__(16) char As[2][12 * 64 * 16];   // 24,576 B

    const int tid   = threadIdx.x;
    const int lane  = tid & 63;
    const int wave  = tid >> 6;          // 0..7
    const int quad  = lane >> 4;
    const int l16   = lane & 15;
    const int coutg = wave & 3;          // cout group of 32
    const int rowg  = wave >> 2;         // 0..1 row group of 32

    const int batch = blockIdx.x & 7;    // XCD affinity (round-robin %8)
    const int t2    = blockIdx.x >> 3;   // 0..91
    const int half  = t2 & 1;
    const int rb    = t2 >> 1;           // 0..45
    const int row0  = rb * 64;           // within batch

    // staging identity: lane = local row, clamped to batch range
    const int rl0 = row0 + lane;
    const int rcl = rl0 < SPAT ? rl0 : SPAT - 1;
    const int ohh = rcl / 54, oww = rcl - (rcl / 54) * 54;
    const size_t pb = (size_t)batch * CIMG + ohh * HIN + oww;  // pixel index
    const size_t sb = ((size_t)batch * IMG + ohh * HIN + oww) * 64;

    floatx4 acc[2][2] = {};

    auto stage = [&](int chunkAbs, int buf) {
        int gbase = chunkAbs * 12;
#pragma unroll
        for (int j = 0; j < 2; ++j) {
            int gl = j ? 8 + wave : wave;    // LDS slot 0..11 (wave-uniform)
            if (j && wave >= 4) break;
            int g  = gbase + gl;             // global k/8 index 0..647
            const char* src;
            if (g < 576) {                   // spline planes
                int c  = g / 9;
                int rs = g - 9 * c;
                int rw = rs / 3;
                int off = c * IMG + rw * HIN + (rs - rw * 3);
                src = (const char*)(act8 + (pb + off) * 8);
            } else {                         // base/silu planes
                int eb = g - 576;
                int rs = eb >> 3;
                int rw = rs / 3;
                int off = (rw * HIN + (rs - rw * 3)) * 64 + (eb & 7) * 8;
                src = (const char*)(silu_t + sb + off);
            }
            GL2LDS(src, &As[buf][gl * 1024]);
        }
    };

    const int cstart = half * NCH;

    stage(cstart, 0);
    __syncthreads();

    for (int i = 0; i < NCH; ++i) {
        const int buf = i & 1;
        if (i + 1 < NCH) stage(cstart + i + 1, buf ^ 1);   // async prefetch

        const int chunkAbs = cstart + i;
#pragma unroll
        for (int ks = 0; ks < 3; ++ks) {
            int gq = (chunkAbs * 3 + ks) * 4 + quad;
            bf16x8 wfr[2], afr[2];
#pragma unroll
            for (int nt = 0; nt < 2; ++nt)
                wfr[nt] = *(const bf16x8*)(W2 +
                    ((size_t)gq * 128 + coutg * 32 + nt * 16 + l16) * 8);
#pragma unroll
            for (int mt = 0; mt < 2; ++mt)
                afr[mt] = *(const bf16x8*)(&As[buf][
                    ((ks * 4 + quad) * 64 + rowg * 32 + mt * 16 + l16) * 16]);
#pragma unroll
            for (int mt = 0; mt < 2; ++mt)
#pragma unroll
                for (int nt = 0; nt < 2; ++nt)
                    acc[mt][nt] = __builtin_amdgcn_mfma_f32_16x16x32_bf16(
                        wfr[nt], afr[mt], acc[mt][nt], 0, 0, 0);
        }
        __syncthreads();
    }

    // epilogue: D col(l16) = local row, D row(quad*4+r) = cout -> coalesced
#pragma unroll
    for (int mt = 0; mt < 2; ++mt) {
        int rl = row0 + rowg * 32 + mt * 16 + l16;   // row within batch
        if (rl < SPAT) {
#pragma unroll
            for (int nt = 0; nt < 2; ++nt) {
#pragma unroll
                for (int r = 0; r < 4; ++r) {
                    int o = coutg * 32 + nt * 16 + quad * 4 + r;
                    size_t idx = (size_t)(batch * 128 + o) * SPAT + rl;
                    float v = acc[mt][nt][r];
                    if (MODE == 0) part[(size_t)half * NOUT + idx] = v;
                    else           atomicAdd(&outp[idx], v);
                }
            }
        }
    }
}

__global__ __launch_bounds__(256) void reduce_kernel(
    const char* __restrict__ ws, float* __restrict__ outp)
{
    const floatx4* p0 = (const floatx4*)(ws + PART_OFF);
    const floatx4* p1 = p0 + NOUT / 4;
    int i = blockIdx.x * 256 + threadIdx.x;   // grid covers NOUT/4 exactly
    floatx4 a = p0[i], b = p1[i];
    ((floatx4*)outp)[i] = (floatx4){a[0] + b[0], a[1] + b[1],
                                    a[2] + b[2], a[3] + b[3]};
}

__global__ __launch_bounds__(256) void zero_kernel(float* __restrict__ outp)
{
    int i = blockIdx.x * 256 + threadIdx.x;
    ((floatx4*)outp)[i] = (floatx4){0.f, 0.f, 0.f, 0.f};
}

extern "C" void kernel_launch(void* const* d_in, const int* in_sizes, int n_in,
                              void* d_out, int out_size, void* d_ws, size_t ws_size,
                              hipStream_t stream) {
    const float* x  = (const float*)d_in[0];
    const float* bw = (const float*)d_in[1];
    const float* sw = (const float*)d_in[2];
    const float* sc = (const float*)d_in[3];
    float* out = (float*)d_out;
    char*  ws  = (char*)d_ws;

    prep_kernel<<<R_ACT_END / 256, 256, 0, stream>>>(x, bw, sw, sc, ws);

    if (ws_size >= WS_NEED) {
        kan_gemm<0><<<8 * RBPB * 2, 512, 0, stream>>>(ws, out);
        reduce_kernel<<<NOUT / 4 / 256, 256, 0, stream>>>(ws, out);
    } else {
        zero_kernel<<<NOUT / 4 / 256, 256, 0, stream>>>(out);
        kan_gemm<1><<<8 * RBPB * 2, 512, 0, stream>>>(ws, out);
    }
}